// Round 2
// baseline (324.592 us; speedup 1.0000x reference)
//
#include <hip/hip_runtime.h>
#include <hip/hip_bf16.h>

// B=16384; per batch, Gram of the 27x128 fp32 matrix [dense(1x128); sparse(26x128)].
// Output row (fp32): [dense(128) | sd(26) | triu pairs(325)] = 479.
// Compute: bf16 MFMA 16x16x32 (fp32 accum). Input rounding error ~0.25 max << 1.28 threshold.
#define NBATCH 16384
#define NF 26
#define ND 128
#define RSTRIDE 136   // padded LDS row stride (bf16 elems): 272B; ds_read_b128 lands 2-way/bank (free, m136)
#define BPB 4         // batches per block: A 34816B + stage 7664B = 42480B LDS -> 3 blocks/CU
#define OUTW 479

typedef __attribute__((ext_vector_type(8))) __bf16 bf16x8;
typedef __attribute__((ext_vector_type(4))) float floatx4;

__global__ __launch_bounds__(256, 3)
void interaction_kernel(const float* __restrict__ dense,
                        const float* __restrict__ sparse,
                        float* __restrict__ out)
{
    // A: per batch 32 rows bf16 (row 0 = dense, 1..26 = sparse, 27..31 zeroed)
    __shared__ __align__(16) __bf16 A[BPB * 32 * RSTRIDE];
    __shared__ __align__(16) float  stage[BPB * OUTW];

    const int t   = threadIdx.x;
    const int blk = blockIdx.x;
    const int b0  = blk * BPB;

    // ---- global fp32 -> LDS bf16: BPB*32 rows x 32 chunks of 4 floats ----
    for (int c = t; c < BPB * 32 * 32; c += 256) {
        int batch = c >> 10;           // 32*32 = 1024 chunks per batch
        int rem   = c & 1023;
        int row   = rem >> 5;          // 0..31
        int col   = (rem & 31) << 2;   // float column, multiple of 4
        __bf16 b4[4];
        if (row < 27) {
            const float* src = (row == 0)
                ? dense  + (size_t)(b0 + batch) * ND + col
                : sparse + ((size_t)(b0 + batch) * NF + (row - 1)) * ND + col;
            float4 v = *(const float4*)src;
            b4[0] = (__bf16)v.x; b4[1] = (__bf16)v.y;
            b4[2] = (__bf16)v.z; b4[3] = (__bf16)v.w;
            if (row == 0) {  // dense passthrough stays exact fp32
                float* sb = &stage[batch * OUTW + col];
                sb[0] = v.x; sb[1] = v.y; sb[2] = v.z; sb[3] = v.w;
            }
        } else {
            b4[0] = b4[1] = b4[2] = b4[3] = (__bf16)0.0f;  // deterministic pad rows
        }
        *(uint2*)&A[(batch * 32 + row) * RSTRIDE + col] = *(const uint2*)b4;
    }
    __syncthreads();

    const int wave = t >> 6;       // 4 waves -> 1 batch each
    const int lane = t & 63;
    const int quad = lane >> 4;
    const int lrow = lane & 15;

    // ---- Gram via MFMA: for M*M^T the A-frag and B-frag lane layouts coincide ----
    {
        const int batch = wave;
        const __bf16* Ab = &A[batch * 32 * RSTRIDE];
        bf16x8 f0[4], f1[4];
        #pragma unroll
        for (int k = 0; k < 4; ++k) {
            const int koff = k * 32 + quad * 8;
            f0[k] = *(const bf16x8*)&Ab[lrow * RSTRIDE + koff];          // rows 0..15
            f1[k] = *(const bf16x8*)&Ab[(16 + lrow) * RSTRIDE + koff];   // rows 16..31
        }
        floatx4 c00 = {0.f, 0.f, 0.f, 0.f};
        floatx4 c01 = {0.f, 0.f, 0.f, 0.f};
        floatx4 c11 = {0.f, 0.f, 0.f, 0.f};
        #pragma unroll
        for (int k = 0; k < 4; ++k) {
            c00 = __builtin_amdgcn_mfma_f32_16x16x32_bf16(f0[k], f0[k], c00, 0, 0, 0);
            c01 = __builtin_amdgcn_mfma_f32_16x16x32_bf16(f0[k], f1[k], c01, 0, 0, 0);
            c11 = __builtin_amdgcn_mfma_f32_16x16x32_bf16(f1[k], f1[k], c11, 0, 0, 0);
        }

        // C/D layout (16x16x32): col = lane&15, row = quad*4 + reg   [m89/m91]
        float* sb = &stage[batch * OUTW];
        auto scatter = [&](int r, int c, float v) {
            // gram coords r,c in [0,31]; valid: c<=26 and r<c (0 = dense row)
            if (c <= NF && r < c) {
                int idx = (r == 0)
                    ? (ND - 1 + c)                                         // sd: 128 + (c-1)
                    : (ND + NF + (((r - 1) * (52 - r)) >> 1) + c - r - 1); // pairs, base 154
                sb[idx] = v;
            }
        };
        #pragma unroll
        for (int rr = 0; rr < 4; ++rr) {
            int r = quad * 4 + rr;
            scatter(r,      lrow,      c00[rr]);   // tile (0,0)
            scatter(r,      16 + lrow, c01[rr]);   // tile (0,1)
            scatter(16 + r, 16 + lrow, c11[rr]);   // tile (1,1)
        }
    }
    __syncthreads();

    // ---- stage -> global: BPB*479 floats = 7664 B = 479 x 16B chunks, block base 16B-aligned ----
    const size_t outbase = (size_t)blk * (BPB * OUTW);
    for (int c = t; c < (BPB * OUTW) / 4; c += 256) {
        *(uint4*)&out[outbase + c * 4] = *(const uint4*)&stage[c * 4];
    }
}

extern "C" void kernel_launch(void* const* d_in, const int* in_sizes, int n_in,
                              void* d_out, int out_size, void* d_ws, size_t ws_size,
                              hipStream_t stream) {
    const float* dense  = (const float*)d_in[0];
    const float* sparse = (const float*)d_in[1];
    float* out = (float*)d_out;
    dim3 grid(NBATCH / BPB);
    dim3 block(256);
    hipLaunchKernelGGL(interaction_kernel, grid, block, 0, stream, dense, sparse, out);
}

// Round 3
// 309.633 us; speedup vs baseline: 1.0483x; 1.0483x over previous
//
#include <hip/hip_runtime.h>
#include <hip/hip_bf16.h>

// B=16384; per batch, Gram of the 27x128 fp32 matrix [dense(1x128); sparse(26x128)].
// Output row (fp32): [dense(128) | sd(26) | triu pairs(325)] = 479.
// bf16 MFMA 16x16x32, fragments loaded DIRECTLY global->register (no LDS A-tile):
// for M*M^T the A- and B-operand lane layouts coincide, and each lane's fragment
// is 8 contiguous elements of one row -> two dwordx4 loads, branch-free.
#define NBATCH 16384
#define NF 26
#define ND 128
#define BPB 4         // batches per block = 4 waves; LDS = output stage only (7664 B)
#define OUTW 479

typedef __attribute__((ext_vector_type(8))) __bf16 bf16x8;
typedef __attribute__((ext_vector_type(4))) float floatx4;

__device__ __forceinline__ bf16x8 cvt8(float4 a, float4 b) {
    return (bf16x8){(__bf16)a.x, (__bf16)a.y, (__bf16)a.z, (__bf16)a.w,
                    (__bf16)b.x, (__bf16)b.y, (__bf16)b.z, (__bf16)b.w};
}

__global__ __launch_bounds__(256, 4)
void interaction_kernel(const float* __restrict__ dense,
                        const float* __restrict__ sparse,
                        float* __restrict__ out)
{
    __shared__ __align__(16) float stage[BPB * OUTW];

    const int t    = threadIdx.x;
    const int blk  = blockIdx.x;
    const int b0   = blk * BPB;
    const int wave = t >> 6;
    const int lane = t & 63;
    const int quad = lane >> 4;   // 0..3
    const int lrow = lane & 15;   // 0..15

    // ---- dense passthrough: 4 batches x 32 uint4 chunks, coalesced ----
    if (t < BPB * 32) {
        int batch = t >> 5, chunk = t & 31;
        *(float4*)&stage[batch * OUTW + chunk * 4] =
            *(const float4*)&dense[(size_t)(b0 + batch) * ND + chunk * 4];
    }

    // ---- fragment loads: one batch per wave, 16 dwordx4 loads/lane, no branches ----
    const int batch = b0 + wave;
    // f0 covers Gram rows 0..15: row 0 = dense, rows 1..15 = sparse rows 0..14
    const float* base0 = (lrow == 0)
        ? dense  + (size_t)batch * ND
        : sparse + ((size_t)batch * NF + (lrow - 1)) * ND;
    // f1 covers Gram rows 16..31 = sparse rows 15..26; lrow>=11 is OOB -> clamp
    // to row 25 (those Gram rows/cols >= 27 are masked at scatter)
    int r1 = 15 + lrow; if (r1 > NF - 1) r1 = NF - 1;
    const float* base1 = sparse + ((size_t)batch * NF + r1) * ND;

    bf16x8 f0[4], f1[4];
    #pragma unroll
    for (int k = 0; k < 4; ++k) {
        const int off = k * 32 + quad * 8;
        float4 a0 = *(const float4*)(base0 + off);
        float4 a1 = *(const float4*)(base0 + off + 4);
        float4 c0 = *(const float4*)(base1 + off);
        float4 c1 = *(const float4*)(base1 + off + 4);
        f0[k] = cvt8(a0, a1);
        f1[k] = cvt8(c0, c1);
    }

    floatx4 c00 = {0.f, 0.f, 0.f, 0.f};
    floatx4 c01 = {0.f, 0.f, 0.f, 0.f};
    floatx4 c11 = {0.f, 0.f, 0.f, 0.f};
    #pragma unroll
    for (int k = 0; k < 4; ++k) {
        c00 = __builtin_amdgcn_mfma_f32_16x16x32_bf16(f0[k], f0[k], c00, 0, 0, 0);
        c01 = __builtin_amdgcn_mfma_f32_16x16x32_bf16(f0[k], f1[k], c01, 0, 0, 0);
        c11 = __builtin_amdgcn_mfma_f32_16x16x32_bf16(f1[k], f1[k], c11, 0, 0, 0);
    }

    // ---- scatter to stage. C/D layout (16x16x32): col = lane&15, row = quad*4+reg ----
    {
        float* sb = &stage[wave * OUTW];
        auto scatter = [&](int r, int c, float v) {
            // gram coords r,c in [0,31]; valid: c<=26 and r<c (row/col 0 = dense)
            if (c <= NF && r < c) {
                int idx = (r == 0)
                    ? (ND - 1 + c)                                         // sd: 128 + (c-1)
                    : (ND + NF + (((r - 1) * (52 - r)) >> 1) + c - r - 1); // pairs, base 154
                sb[idx] = v;
            }
        };
        #pragma unroll
        for (int rr = 0; rr < 4; ++rr) {
            int r = quad * 4 + rr;
            scatter(r,      lrow,      c00[rr]);   // tile (0,0)
            scatter(r,      16 + lrow, c01[rr]);   // tile (0,1)
            scatter(16 + r, 16 + lrow, c11[rr]);   // tile (1,1)
        }
    }
    __syncthreads();

    // ---- stage -> global: 4*479 floats = 7664 B = 479 x 16B chunks, block base 16B-aligned ----
    const size_t outbase = (size_t)blk * (BPB * OUTW);
    for (int c = t; c < (BPB * OUTW) / 4; c += 256) {
        *(uint4*)&out[outbase + c * 4] = *(const uint4*)&stage[c * 4];
    }
}

extern "C" void kernel_launch(void* const* d_in, const int* in_sizes, int n_in,
                              void* d_out, int out_size, void* d_ws, size_t ws_size,
                              hipStream_t stream) {
    const float* dense  = (const float*)d_in[0];
    const float* sparse = (const float*)d_in[1];
    float* out = (float*)d_out;
    dim3 grid(NBATCH / BPB);
    dim3 block(256);
    hipLaunchKernelGGL(interaction_kernel, grid, block, 0, stream, dense, sparse, out);
}